// Round 2
// baseline (659.400 us; speedup 1.0000x reference)
//
#include <hip/hip_runtime.h>
#include <hip/hip_bf16.h>

typedef __attribute__((ext_vector_type(8))) short bf16x8;
typedef __attribute__((ext_vector_type(4))) float f32x4;

__device__ __forceinline__ unsigned short f2bf(float f) {
  __hip_bfloat16 h = __float2bfloat16(f);
  return *reinterpret_cast<unsigned short*>(&h);
}

__device__ __forceinline__ void gld_lds16(void* lds, const void* g) {
  __builtin_amdgcn_global_load_lds(
      (const __attribute__((address_space(1))) unsigned int*)g,
      (__attribute__((address_space(3))) unsigned int*)lds, 16, 0, 0);
}

// ---------------------------------------------------------------------------
// Kernel 1: offset conv (fp64 accumulate) + gather + fp32->bf16 cast.
// One block per (b, h) image row. 256 threads: thread t handles pixel w=t&127,
// channel-half (t>>7) of each 32-channel chunk.
// Index math stays ENTIRELY in fp64 to match the harness's np (float64) ref:
// fp32 rounding at |y|~64 has ~4e-6 absolute noise -> ~4 expected trunc flips.
// ---------------------------------------------------------------------------
__global__ __launch_bounds__(256) void k1_offs_gather(
    const float* __restrict__ in, const float* __restrict__ w_off,
    const float* __restrict__ b_off, unsigned short* __restrict__ samp) {
  __shared__ float tile[3][128][34];   // stride 34 to spread banks
  __shared__ float wlf[9 * 64];        // [tap][c(32)][o(2)] for current chunk
  __shared__ double dsum[2][128][2];
  __shared__ int lin_lds[128];

  const int bid = blockIdx.x;          // 0..2047  = b*128 + h
  const int b = bid >> 7, h = bid & 127;
  const int t = threadIdx.x;
  const int w = t & 127, half = t >> 7, ch0 = half * 16;

  double a0 = 0.0, a1 = 0.0;

  for (int c0 = 0; c0 < 256; c0 += 32) {
    __syncthreads();  // protect tile/wlf from previous chunk's readers
    // weights slice for this chunk: contiguous 64 floats per tap
    for (int i = t; i < 576; i += 256) {
      int tap = i >> 6, r = i & 63;
      wlf[i] = w_off[tap * 512 + c0 * 2 + r];
    }
    // input rows h-1..h+1, 128 w, 32 channels
    for (int dr = 0; dr < 3; ++dr) {
      int hh = h + dr - 1;
      if ((unsigned)hh < 128u) {
        const float* rbase = in + ((size_t)(b * 128 + hh) * 128) * 256 + c0;
        #pragma unroll
        for (int it = 0; it < 4; ++it) {
          int idx = it * 256 + t;      // 0..1023
          int ww = idx >> 3, cq = idx & 7;
          const float4 v = *(const float4*)(rbase + ww * 256 + cq * 4);
          float* dst = &tile[dr][ww][cq * 4];
          *(float2*)dst = make_float2(v.x, v.y);
          *(float2*)(dst + 2) = make_float2(v.z, v.w);
        }
      } else {
        #pragma unroll
        for (int it = 0; it < 4; ++it) {
          int idx = it * 256 + t;
          int ww = idx >> 3, cq = idx & 7;
          float* dst = &tile[dr][ww][cq * 4];
          *(float2*)dst = make_float2(0.f, 0.f);
          *(float2*)(dst + 2) = make_float2(0.f, 0.f);
        }
      }
    }
    __syncthreads();
    // accumulate 9 taps x 16 channels in fp64
    #pragma unroll
    for (int dr = 0; dr < 3; ++dr) {
      #pragma unroll
      for (int dc = 0; dc < 3; ++dc) {
        int wsrc = w + dc - 1;
        if ((unsigned)wsrc >= 128u) continue;
        const float2* tp2 = (const float2*)&tile[dr][wsrc][ch0];
        const float2* wp2 = (const float2*)&wlf[(dr * 3 + dc) * 64 + ch0 * 2];
        #pragma unroll
        for (int c2 = 0; c2 < 8; ++c2) {
          float2 v = tp2[c2];
          float2 wa = wp2[2 * c2];      // channel 2*c2:   (o0, o1)
          float2 wb = wp2[2 * c2 + 1];  // channel 2*c2+1: (o0, o1)
          a0 += (double)v.x * (double)wa.x;
          a1 += (double)v.x * (double)wa.y;
          a0 += (double)v.y * (double)wb.x;
          a1 += (double)v.y * (double)wb.y;
        }
      }
    }
  }
  dsum[half][w][0] = a0;
  dsum[half][w][1] = a1;
  __syncthreads();
  if (t < 128) {
    double o0 = dsum[0][t][0] + dsum[1][t][0] + (double)b_off[0];
    double o1 = dsum[0][t][1] + dsum[1][t][1] + (double)b_off[1];
    // pure fp64: add, clip, truncate (values non-negative after clip)
    double yd = (double)h + o0;
    double xd = (double)t + o1;
    yd = yd < 0.0 ? 0.0 : (yd > 127.0 ? 127.0 : yd);
    xd = xd < 0.0 ? 0.0 : (xd > 127.0 ? 127.0 : xd);
    int y = (int)yd, x = (int)xd;
    lin_lds[t] = y * 128 + x;
  }
  __syncthreads();
  // gather + cast: 128 px * 256 ch, one wave reads one pixel's 1KB per iter
  const float* imgbase = in + (size_t)b * 16384 * 256;
  unsigned short* obase = samp + (size_t)bid * 128 * 256;
  for (int it = 0; it < 32; ++it) {
    int idx = it * 256 + t;
    int px = idx >> 6, cv = idx & 63;
    const float4 v = *(const float4*)(imgbase + (size_t)lin_lds[px] * 256 + cv * 4);
    ushort4 o;
    o.x = f2bf(v.x); o.y = f2bf(v.y); o.z = f2bf(v.z); o.w = f2bf(v.w);
    *(ushort4*)(obase + px * 256 + cv * 4) = o;
  }
}

// ---------------------------------------------------------------------------
// Kernel 2: w_def (3,3,256,256)[tap][k][n] fp32 -> wT[tap][n][k] bf16
// ---------------------------------------------------------------------------
__global__ __launch_bounds__(256) void k2_wT(const float* __restrict__ wdef,
                                             unsigned short* __restrict__ wT) {
  int g = blockIdx.x * 256 + threadIdx.x;  // 0..589823
  int tap = g >> 16;
  int n = (g >> 8) & 255;
  int k = g & 255;
  wT[g] = f2bf(wdef[((size_t)tap * 256 + k) * 256 + n]);
}

// ---------------------------------------------------------------------------
// Kernel 3: implicit-GEMM 3x3 SAME conv, bf16 MFMA (m97 structure).
// Tile: 128 pixels (one (b,h) row) x 128 out-channels, BK=64, 36 K-steps.
// Grid 4096 = 2048 M-tiles x 2 N-tiles. 256 threads = 4 waves (2x2 of 64x64).
// ---------------------------------------------------------------------------
__global__ __launch_bounds__(256) void k3_conv(
    const unsigned short* __restrict__ samp, const unsigned short* __restrict__ wT,
    const float* __restrict__ b_def, float* __restrict__ out,
    const unsigned short* __restrict__ zerobuf) {
  __shared__ unsigned short Asm[128 * 64];
  __shared__ unsigned short Bsm[128 * 64];
  const int bid = blockIdx.x;
  const int mt = bid >> 1, nt = bid & 1;
  const int b = mt >> 7, h = mt & 127;
  const int tid = threadIdx.x;
  const int lane = tid & 63, wave = tid >> 6;
  const int wr = wave >> 1, wc = wave & 1;
  const int rbase = tid >> 3;  // 0..31: lds row group
  const int ch = tid & 7;      // 16B chunk within 64-ch row
  const int r15 = lane & 15, g4 = lane >> 4;

  f32x4 acc[4][4];
  #pragma unroll
  for (int i = 0; i < 4; ++i)
    #pragma unroll
    for (int j = 0; j < 4; ++j) acc[i][j] = (f32x4){0.f, 0.f, 0.f, 0.f};

  for (int tap = 0; tap < 9; ++tap) {
    const int dr = tap / 3 - 1, dc = tap % 3 - 1;
    const int hs = h + dr;
    const bool hv = (unsigned)hs < 128u;
    const unsigned short* arow = samp + (size_t)((b * 128 + hs) * 128) * 256;
    const unsigned short* btap = wT + ((size_t)tap * 256 + nt * 128) * 256;
    for (int kc = 0; kc < 4; ++kc) {
      const int k0 = kc * 64;
      __syncthreads();
      #pragma unroll
      for (int it = 0; it < 4; ++it) {  // stage A: 128 rows x 64 ch bf16
        int row = it * 32 + rbase;
        int wsrc = row + dc;
        const unsigned short* src = (hv && (unsigned)wsrc < 128u)
            ? (arow + (size_t)wsrc * 256 + k0 + ch * 8)
            : (zerobuf + ch * 8);
        gld_lds16(&Asm[(it * 256 + tid) * 8], src);
      }
      #pragma unroll
      for (int it = 0; it < 4; ++it) {  // stage B: 128 n x 64 k bf16
        int n = it * 32 + rbase;
        gld_lds16(&Bsm[(it * 256 + tid) * 8], btap + (size_t)n * 256 + k0 + ch * 8);
      }
      __syncthreads();
      #pragma unroll
      for (int kk = 0; kk < 2; ++kk) {
        const int kcol = kk * 32 + g4 * 8;
        bf16x8 af[4], bfr[4];
        #pragma unroll
        for (int mi = 0; mi < 4; ++mi)
          af[mi] = *(const bf16x8*)&Asm[(wr * 64 + mi * 16 + r15) * 64 + kcol];
        #pragma unroll
        for (int ni = 0; ni < 4; ++ni)
          bfr[ni] = *(const bf16x8*)&Bsm[(wc * 64 + ni * 16 + r15) * 64 + kcol];
        #pragma unroll
        for (int mi = 0; mi < 4; ++mi)
          #pragma unroll
          for (int ni = 0; ni < 4; ++ni)
            acc[mi][ni] = __builtin_amdgcn_mfma_f32_16x16x32_bf16(
                af[mi], bfr[ni], acc[mi][ni], 0, 0, 0);
      }
    }
  }
  // epilogue: +bias, fp32 store
  const int colg = nt * 128 + wc * 64 + r15;
  float bias[4];
  #pragma unroll
  for (int ni = 0; ni < 4; ++ni) bias[ni] = b_def[colg + ni * 16];
  #pragma unroll
  for (int mi = 0; mi < 4; ++mi) {
    int r0 = wr * 64 + mi * 16 + g4 * 4;
    #pragma unroll
    for (int j = 0; j < 4; ++j) {
      float* orow = out + ((size_t)mt * 128 + r0 + j) * 256 + colg;
      #pragma unroll
      for (int ni = 0; ni < 4; ++ni) orow[ni * 16] = acc[mi][ni][j] + bias[ni];
    }
  }
}

extern "C" void kernel_launch(void* const* d_in, const int* in_sizes, int n_in,
                              void* d_out, int out_size, void* d_ws, size_t ws_size,
                              hipStream_t stream) {
  const float* in = (const float*)d_in[0];     // (16,128,128,256)
  const float* w_off = (const float*)d_in[1];  // (3,3,256,2)
  const float* b_off = (const float*)d_in[2];  // (2,)
  const float* w_def = (const float*)d_in[3];  // (3,3,256,256)
  const float* b_def = (const float*)d_in[4];  // (256,)
  float* out = (float*)d_out;

  char* ws = (char*)d_ws;
  unsigned short* zerobuf = (unsigned short*)ws;                 // 4 KB zeros
  unsigned short* wT = (unsigned short*)(ws + 4096);             // 1,179,648 B
  unsigned short* samp = (unsigned short*)(ws + 4096 + 1179648); // 134,217,728 B

  hipMemsetAsync(ws, 0, 4096, stream);
  hipLaunchKernelGGL(k2_wT, dim3(2304), dim3(256), 0, stream, w_def, wT);
  hipLaunchKernelGGL(k1_offs_gather, dim3(2048), dim3(256), 0, stream,
                     in, w_off, b_off, samp);
  hipLaunchKernelGGL(k3_conv, dim3(4096), dim3(256), 0, stream,
                     samp, wT, b_def, out, zerobuf);
}

// Round 3
// 539.696 us; speedup vs baseline: 1.2218x; 1.2218x over previous
//
#include <hip/hip_runtime.h>
#include <hip/hip_bf16.h>

typedef __attribute__((ext_vector_type(8))) short bf16x8;
typedef __attribute__((ext_vector_type(4))) float f32x4;

__device__ __forceinline__ unsigned short f2bf(float f) {
  __hip_bfloat16 h = __float2bfloat16(f);
  return *reinterpret_cast<unsigned short*>(&h);
}

__device__ __forceinline__ void gld_lds16(void* lds, const void* g) {
  __builtin_amdgcn_global_load_lds(
      (const __attribute__((address_space(1))) unsigned int*)g,
      (__attribute__((address_space(3))) unsigned int*)lds, 16, 0, 0);
}

// ---------------------------------------------------------------------------
// Kernel 1: offset conv (fp64 accumulate) + gather + fp32->bf16 cast.
// (unchanged from round 2 — passing; optimize after k3 lands)
// ---------------------------------------------------------------------------
__global__ __launch_bounds__(256) void k1_offs_gather(
    const float* __restrict__ in, const float* __restrict__ w_off,
    const float* __restrict__ b_off, unsigned short* __restrict__ samp) {
  __shared__ float tile[3][128][34];
  __shared__ float wlf[9 * 64];
  __shared__ double dsum[2][128][2];
  __shared__ int lin_lds[128];

  const int bid = blockIdx.x;
  const int b = bid >> 7, h = bid & 127;
  const int t = threadIdx.x;
  const int w = t & 127, half = t >> 7, ch0 = half * 16;

  double a0 = 0.0, a1 = 0.0;

  for (int c0 = 0; c0 < 256; c0 += 32) {
    __syncthreads();
    for (int i = t; i < 576; i += 256) {
      int tap = i >> 6, r = i & 63;
      wlf[i] = w_off[tap * 512 + c0 * 2 + r];
    }
    for (int dr = 0; dr < 3; ++dr) {
      int hh = h + dr - 1;
      if ((unsigned)hh < 128u) {
        const float* rbase = in + ((size_t)(b * 128 + hh) * 128) * 256 + c0;
        #pragma unroll
        for (int it = 0; it < 4; ++it) {
          int idx = it * 256 + t;
          int ww = idx >> 3, cq = idx & 7;
          const float4 v = *(const float4*)(rbase + ww * 256 + cq * 4);
          float* dst = &tile[dr][ww][cq * 4];
          *(float2*)dst = make_float2(v.x, v.y);
          *(float2*)(dst + 2) = make_float2(v.z, v.w);
        }
      } else {
        #pragma unroll
        for (int it = 0; it < 4; ++it) {
          int idx = it * 256 + t;
          int ww = idx >> 3, cq = idx & 7;
          float* dst = &tile[dr][ww][cq * 4];
          *(float2*)dst = make_float2(0.f, 0.f);
          *(float2*)(dst + 2) = make_float2(0.f, 0.f);
        }
      }
    }
    __syncthreads();
    #pragma unroll
    for (int dr = 0; dr < 3; ++dr) {
      #pragma unroll
      for (int dc = 0; dc < 3; ++dc) {
        int wsrc = w + dc - 1;
        if ((unsigned)wsrc >= 128u) continue;
        const float2* tp2 = (const float2*)&tile[dr][wsrc][ch0];
        const float2* wp2 = (const float2*)&wlf[(dr * 3 + dc) * 64 + ch0 * 2];
        #pragma unroll
        for (int c2 = 0; c2 < 8; ++c2) {
          float2 v = tp2[c2];
          float2 wa = wp2[2 * c2];
          float2 wb = wp2[2 * c2 + 1];
          a0 += (double)v.x * (double)wa.x;
          a1 += (double)v.x * (double)wa.y;
          a0 += (double)v.y * (double)wb.x;
          a1 += (double)v.y * (double)wb.y;
        }
      }
    }
  }
  dsum[half][w][0] = a0;
  dsum[half][w][1] = a1;
  __syncthreads();
  if (t < 128) {
    double o0 = dsum[0][t][0] + dsum[1][t][0] + (double)b_off[0];
    double o1 = dsum[0][t][1] + dsum[1][t][1] + (double)b_off[1];
    double yd = (double)h + o0;
    double xd = (double)t + o1;
    yd = yd < 0.0 ? 0.0 : (yd > 127.0 ? 127.0 : yd);
    xd = xd < 0.0 ? 0.0 : (xd > 127.0 ? 127.0 : xd);
    int y = (int)yd, x = (int)xd;
    lin_lds[t] = y * 128 + x;
  }
  __syncthreads();
  const float* imgbase = in + (size_t)b * 16384 * 256;
  unsigned short* obase = samp + (size_t)bid * 128 * 256;
  for (int it = 0; it < 32; ++it) {
    int idx = it * 256 + t;
    int px = idx >> 6, cv = idx & 63;
    const float4 v = *(const float4*)(imgbase + (size_t)lin_lds[px] * 256 + cv * 4);
    ushort4 o;
    o.x = f2bf(v.x); o.y = f2bf(v.y); o.z = f2bf(v.z); o.w = f2bf(v.w);
    *(ushort4*)(obase + px * 256 + cv * 4) = o;
  }
}

// ---------------------------------------------------------------------------
// Kernel 2: w_def (3,3,256,256)[tap][k][n] fp32 -> wT[tap][n][k] bf16
// ---------------------------------------------------------------------------
__global__ __launch_bounds__(256) void k2_wT(const float* __restrict__ wdef,
                                             unsigned short* __restrict__ wT) {
  int g = blockIdx.x * 256 + threadIdx.x;
  int tap = g >> 16;
  int n = (g >> 8) & 255;
  int k = g & 255;
  wT[g] = f2bf(wdef[((size_t)tap * 256 + k) * 256 + n]);
}

// ---------------------------------------------------------------------------
// Kernel 3: implicit-GEMM 3x3 SAME conv, bf16 MFMA.
// BM=256 (2 image rows), BN=256 (all F), BK=32. 72 K-steps (9 taps x 8 kc).
// 512 threads = 8 waves (2M x 4N), per-wave 128x64 output (acc[8][4]).
// 4-deep LDS ring (4 x (16KB A + 16KB B) = 128 KB), counted vmcnt(12) --
// never drains to 0 in the main loop. Raw s_barrier (no __syncthreads drain).
// LDS XOR swizzle: byte ^= ((byte>>7)&3)<<4  (involution, 16B granules) --
// applied on per-lane GLOBAL source (write side, rule #21) and on ds_read
// address (read side). Spreads 16-row fragment reads over all 32 banks.
// ---------------------------------------------------------------------------
__global__ __launch_bounds__(512, 2) void k3_conv(
    const unsigned short* __restrict__ samp, const unsigned short* __restrict__ wT,
    const float* __restrict__ b_def, float* __restrict__ out,
    const unsigned short* __restrict__ zerobuf) {
  __shared__ __align__(16) unsigned char smem[131072];  // A ring 64KB | B ring 64KB

  // T1: bijective XCD swizzle (grid 1024, 1024%8==0): 128 consecutive tiles/XCD
  const int bid0 = blockIdx.x;
  const int mt = (bid0 & 7) * 128 + (bid0 >> 3);
  const int bimg = mt >> 6;            // image index 0..15
  const int h0 = (mt & 63) * 2;        // first of 2 image rows in this tile

  const int tid = threadIdx.x;
  const int lane = tid & 63, wave = tid >> 6;
  const int wr = wave >> 2, wc = wave & 3;    // 2M x 4N wave grid
  const int r15 = lane & 15, g4 = lane >> 4;
  const int g4eff = g4 ^ ((r15 >> 1) & 3);    // read-side swizzle (row parity bits)

  // fragment LDS element offsets (row stride 32 elem = 64 B)
  int aoff[8], boff[4];
  #pragma unroll
  for (int mi = 0; mi < 8; ++mi)
    aoff[mi] = (wr * 128 + mi * 16 + r15) * 32 + g4eff * 8;
  #pragma unroll
  for (int ni = 0; ni < 4; ++ni)
    boff[ni] = (wc * 64 + ni * 16 + r15) * 32 + g4eff * 8;

  f32x4 acc[8][4];
  #pragma unroll
  for (int i = 0; i < 8; ++i)
    #pragma unroll
    for (int j = 0; j < 4; ++j) acc[i][j] = (f32x4){0.f, 0.f, 0.f, 0.f};

  // stage K-step ts into ring slot ts&3 (A: 256 rows x 32ch, B: 256 n x 32k)
  auto stage = [&](int ts) {
    const int tap = ts >> 3, kc2 = ts & 7;
    const int q = (tap * 11) >> 5;           // tap/3
    const int dr = q - 1, dc = tap - q * 3 - 1;
    unsigned char* Ad = smem + (size_t)(ts & 3) * 16384;
    unsigned char* Bd = smem + 65536 + (size_t)(ts & 3) * 16384;
    const unsigned short* bt = wT + tap * 65536 + kc2 * 32;
    #pragma unroll
    for (int it = 0; it < 2; ++it) {
      const int slot = it * 512 + tid;       // 0..1023
      const int i = slot >> 2, ch = slot & 3;
      const int chs = ch ^ ((i >> 1) & 3);   // inverse swizzle on global source
      const int hh = h0 + (i >> 7) + dr;
      const int ww = (i & 127) + dc;
      const unsigned short* src =
          ((unsigned)hh < 128u && (unsigned)ww < 128u)
              ? (samp + ((size_t)(bimg * 128 + hh) * 128 + ww) * 256 + kc2 * 32 + chs * 8)
              : (zerobuf + ch * 8);
      gld_lds16(Ad + slot * 16, src);
    }
    #pragma unroll
    for (int it = 0; it < 2; ++it) {
      const int slot = it * 512 + tid;
      const int n = slot >> 2, ch = slot & 3;
      const int chs = ch ^ ((n >> 1) & 3);
      gld_lds16(Bd + slot * 16, bt + n * 256 + chs * 8);
    }
  };

  auto compute = [&](int T) {
    const unsigned short* Ab = (const unsigned short*)(smem + (size_t)(T & 3) * 16384);
    const unsigned short* Bb = (const unsigned short*)(smem + 65536 + (size_t)(T & 3) * 16384);
    bf16x8 af[8], bfr[4];
    #pragma unroll
    for (int mi = 0; mi < 8; ++mi) af[mi] = *(const bf16x8*)(Ab + aoff[mi]);
    #pragma unroll
    for (int ni = 0; ni < 4; ++ni) bfr[ni] = *(const bf16x8*)(Bb + boff[ni]);
    __builtin_amdgcn_s_setprio(1);
    #pragma unroll
    for (int mi = 0; mi < 8; ++mi)
      #pragma unroll
      for (int ni = 0; ni < 4; ++ni)
        acc[mi][ni] = __builtin_amdgcn_mfma_f32_16x16x32_bf16(
            af[mi], bfr[ni], acc[mi][ni], 0, 0, 0);
    __builtin_amdgcn_s_setprio(0);
  };

#define K3_STEP(T, VM)                                      \
  {                                                         \
    if ((T) + 3 < 72) stage((T) + 3);                       \
    asm volatile("s_waitcnt vmcnt(" #VM ")" ::: "memory");  \
    __builtin_amdgcn_s_barrier();                           \
    __builtin_amdgcn_sched_barrier(0);                      \
    compute(T);                                             \
    asm volatile("" ::: "memory");                          \
    __builtin_amdgcn_sched_barrier(0);                      \
    __builtin_amdgcn_s_barrier();                           \
  }

  // prologue: fill 3 ring slots
  stage(0); stage(1); stage(2);
  for (int t = 0; t < 69; ++t) K3_STEP(t, 12);
  K3_STEP(69, 8);
  K3_STEP(70, 4);
  K3_STEP(71, 0);
#undef K3_STEP

  // epilogue: +bias, fp32 store
  const int colg = wc * 64 + r15;
  float bias[4];
  #pragma unroll
  for (int ni = 0; ni < 4; ++ni) bias[ni] = b_def[colg + ni * 16];
  #pragma unroll
  for (int mi = 0; mi < 8; ++mi) {
    const int r0 = wr * 128 + mi * 16 + g4 * 4;
    #pragma unroll
    for (int j = 0; j < 4; ++j) {
      float* orow = out + ((size_t)mt * 256 + r0 + j) * 256 + colg;
      #pragma unroll
      for (int ni = 0; ni < 4; ++ni) orow[ni * 16] = acc[mi][ni][j] + bias[ni];
    }
  }
}

extern "C" void kernel_launch(void* const* d_in, const int* in_sizes, int n_in,
                              void* d_out, int out_size, void* d_ws, size_t ws_size,
                              hipStream_t stream) {
  const float* in = (const float*)d_in[0];     // (16,128,128,256)
  const float* w_off = (const float*)d_in[1];  // (3,3,256,2)
  const float* b_off = (const float*)d_in[2];  // (2,)
  const float* w_def = (const float*)d_in[3];  // (3,3,256,256)
  const float* b_def = (const float*)d_in[4];  // (256,)
  float* out = (float*)d_out;

  char* ws = (char*)d_ws;
  unsigned short* zerobuf = (unsigned short*)ws;                 // 4 KB zeros
  unsigned short* wT = (unsigned short*)(ws + 4096);             // 1,179,648 B
  unsigned short* samp = (unsigned short*)(ws + 4096 + 1179648); // 134,217,728 B

  hipMemsetAsync(ws, 0, 4096, stream);
  hipLaunchKernelGGL(k2_wT, dim3(2304), dim3(256), 0, stream, w_def, wT);
  hipLaunchKernelGGL(k1_offs_gather, dim3(2048), dim3(256), 0, stream,
                     in, w_off, b_off, samp);
  hipLaunchKernelGGL(k3_conv, dim3(1024), dim3(512), 0, stream,
                     samp, wT, b_def, out, zerobuf);
}

// Round 4
// 524.962 us; speedup vs baseline: 1.2561x; 1.0281x over previous
//
#include <hip/hip_runtime.h>
#include <hip/hip_bf16.h>

typedef __attribute__((ext_vector_type(8))) short bf16x8;
typedef __attribute__((ext_vector_type(4))) float f32x4;

__device__ __forceinline__ unsigned short f2bf(float f) {
  __hip_bfloat16 h = __float2bfloat16(f);
  return *reinterpret_cast<unsigned short*>(&h);
}

__device__ __forceinline__ void gld_lds16(void* lds, const void* g) {
  __builtin_amdgcn_global_load_lds(
      (const __attribute__((address_space(1))) unsigned int*)g,
      (__attribute__((address_space(3))) unsigned int*)lds, 16, 0, 0);
}

// ---------------------------------------------------------------------------
// Kernel 1: offset conv (fp64 accumulate) + gather + fp32->bf16 cast.
// (unchanged — near HBM floor for its ~1.3 GB of traffic)
// ---------------------------------------------------------------------------
__global__ __launch_bounds__(256) void k1_offs_gather(
    const float* __restrict__ in, const float* __restrict__ w_off,
    const float* __restrict__ b_off, unsigned short* __restrict__ samp) {
  __shared__ float tile[3][128][34];
  __shared__ float wlf[9 * 64];
  __shared__ double dsum[2][128][2];
  __shared__ int lin_lds[128];

  const int bid = blockIdx.x;
  const int b = bid >> 7, h = bid & 127;
  const int t = threadIdx.x;
  const int w = t & 127, half = t >> 7, ch0 = half * 16;

  double a0 = 0.0, a1 = 0.0;

  for (int c0 = 0; c0 < 256; c0 += 32) {
    __syncthreads();
    for (int i = t; i < 576; i += 256) {
      int tap = i >> 6, r = i & 63;
      wlf[i] = w_off[tap * 512 + c0 * 2 + r];
    }
    for (int dr = 0; dr < 3; ++dr) {
      int hh = h + dr - 1;
      if ((unsigned)hh < 128u) {
        const float* rbase = in + ((size_t)(b * 128 + hh) * 128) * 256 + c0;
        #pragma unroll
        for (int it = 0; it < 4; ++it) {
          int idx = it * 256 + t;
          int ww = idx >> 3, cq = idx & 7;
          const float4 v = *(const float4*)(rbase + ww * 256 + cq * 4);
          float* dst = &tile[dr][ww][cq * 4];
          *(float2*)dst = make_float2(v.x, v.y);
          *(float2*)(dst + 2) = make_float2(v.z, v.w);
        }
      } else {
        #pragma unroll
        for (int it = 0; it < 4; ++it) {
          int idx = it * 256 + t;
          int ww = idx >> 3, cq = idx & 7;
          float* dst = &tile[dr][ww][cq * 4];
          *(float2*)dst = make_float2(0.f, 0.f);
          *(float2*)(dst + 2) = make_float2(0.f, 0.f);
        }
      }
    }
    __syncthreads();
    #pragma unroll
    for (int dr = 0; dr < 3; ++dr) {
      #pragma unroll
      for (int dc = 0; dc < 3; ++dc) {
        int wsrc = w + dc - 1;
        if ((unsigned)wsrc >= 128u) continue;
        const float2* tp2 = (const float2*)&tile[dr][wsrc][ch0];
        const float2* wp2 = (const float2*)&wlf[(dr * 3 + dc) * 64 + ch0 * 2];
        #pragma unroll
        for (int c2 = 0; c2 < 8; ++c2) {
          float2 v = tp2[c2];
          float2 wa = wp2[2 * c2];
          float2 wb = wp2[2 * c2 + 1];
          a0 += (double)v.x * (double)wa.x;
          a1 += (double)v.x * (double)wa.y;
          a0 += (double)v.y * (double)wb.x;
          a1 += (double)v.y * (double)wb.y;
        }
      }
    }
  }
  dsum[half][w][0] = a0;
  dsum[half][w][1] = a1;
  __syncthreads();
  if (t < 128) {
    double o0 = dsum[0][t][0] + dsum[1][t][0] + (double)b_off[0];
    double o1 = dsum[0][t][1] + dsum[1][t][1] + (double)b_off[1];
    double yd = (double)h + o0;
    double xd = (double)t + o1;
    yd = yd < 0.0 ? 0.0 : (yd > 127.0 ? 127.0 : yd);
    xd = xd < 0.0 ? 0.0 : (xd > 127.0 ? 127.0 : xd);
    int y = (int)yd, x = (int)xd;
    lin_lds[t] = y * 128 + x;
  }
  __syncthreads();
  const float* imgbase = in + (size_t)b * 16384 * 256;
  unsigned short* obase = samp + (size_t)bid * 128 * 256;
  for (int it = 0; it < 32; ++it) {
    int idx = it * 256 + t;
    int px = idx >> 6, cv = idx & 63;
    const float4 v = *(const float4*)(imgbase + (size_t)lin_lds[px] * 256 + cv * 4);
    ushort4 o;
    o.x = f2bf(v.x); o.y = f2bf(v.y); o.z = f2bf(v.z); o.w = f2bf(v.w);
    *(ushort4*)(obase + px * 256 + cv * 4) = o;
  }
}

// ---------------------------------------------------------------------------
// Kernel 2: w_def (3,3,256,256)[tap][k][n] fp32 -> wT[tap][n][k] bf16
// ---------------------------------------------------------------------------
__global__ __launch_bounds__(256) void k2_wT(const float* __restrict__ wdef,
                                             unsigned short* __restrict__ wT) {
  int g = blockIdx.x * 256 + threadIdx.x;
  int tap = g >> 16;
  int n = (g >> 8) & 255;
  int k = g & 255;
  wT[g] = f2bf(wdef[((size_t)tap * 256 + k) * 256 + n]);
}

// ---------------------------------------------------------------------------
// Kernel 3: implicit-GEMM 3x3 SAME conv, bf16 MFMA.
// BM=256, BN=256, BK=32, 72 K-steps. 8 waves (2M x 4N), per-wave 128x64.
// 4-deep LDS ring, SINGLE barrier per step:
//   reads(T) -> stage(T+3) -> [32 MFMA, lgkm-gated] -> vmcnt(8) -> s_barrier
// Ledger: stage(T+1) globally complete before reads(T+1): every wave's
//   vmcnt(8) precedes barrier(T); reads(T+1) follow barrier(T).
// Slot write-after-read: reads of slot (T-1)&3 complete before barrier(T-1)
//   (lgkmcnt gates MFMAs, MFMAs precede barrier); stage(T+3) -> same slot is
//   issued after barrier(T-1).  Tail: VM = 4 (T=69), 0 (T=70), none (T=71).
// ---------------------------------------------------------------------------
__global__ __launch_bounds__(512, 2) void k3_conv(
    const unsigned short* __restrict__ samp, const unsigned short* __restrict__ wT,
    const float* __restrict__ b_def, float* __restrict__ out,
    const unsigned short* __restrict__ zerobuf) {
  __shared__ __align__(16) unsigned char smem[131072];  // A ring 64KB | B ring 64KB

  // T1: bijective XCD swizzle (grid 1024 % 8 == 0)
  const int bid0 = blockIdx.x;
  const int mt = (bid0 & 7) * 128 + (bid0 >> 3);
  const int bimg = mt >> 6;
  const int h0 = (mt & 63) * 2;

  const int tid = threadIdx.x;
  const int lane = tid & 63, wave = tid >> 6;
  const int wr = wave >> 2, wc = wave & 3;
  const int r15 = lane & 15, g4 = lane >> 4;
  const int g4eff = g4 ^ ((r15 >> 1) & 3);

  int aoff[8], boff[4];
  #pragma unroll
  for (int mi = 0; mi < 8; ++mi)
    aoff[mi] = (wr * 128 + mi * 16 + r15) * 32 + g4eff * 8;
  #pragma unroll
  for (int ni = 0; ni < 4; ++ni)
    boff[ni] = (wc * 64 + ni * 16 + r15) * 32 + g4eff * 8;

  f32x4 acc[8][4];
  #pragma unroll
  for (int i = 0; i < 8; ++i)
    #pragma unroll
    for (int j = 0; j < 4; ++j) acc[i][j] = (f32x4){0.f, 0.f, 0.f, 0.f};

  auto stage = [&](int ts) {
    const int tap = ts >> 3, kc2 = ts & 7;
    const int q = (tap * 11) >> 5;
    const int dr = q - 1, dc = tap - q * 3 - 1;
    unsigned char* Ad = smem + (size_t)(ts & 3) * 16384;
    unsigned char* Bd = smem + 65536 + (size_t)(ts & 3) * 16384;
    const unsigned short* bt = wT + tap * 65536 + kc2 * 32;
    #pragma unroll
    for (int it = 0; it < 2; ++it) {
      const int slot = it * 512 + tid;
      const int i = slot >> 2, ch = slot & 3;
      const int chs = ch ^ ((i >> 1) & 3);
      const int hh = h0 + (i >> 7) + dr;
      const int ww = (i & 127) + dc;
      const unsigned short* src =
          ((unsigned)hh < 128u && (unsigned)ww < 128u)
              ? (samp + ((size_t)(bimg * 128 + hh) * 128 + ww) * 256 + kc2 * 32 + chs * 8)
              : (zerobuf + ch * 8);
      gld_lds16(Ad + slot * 16, src);
    }
    #pragma unroll
    for (int it = 0; it < 2; ++it) {
      const int slot = it * 512 + tid;
      const int n = slot >> 2, ch = slot & 3;
      const int chs = ch ^ ((n >> 1) & 3);
      gld_lds16(Bd + slot * 16, bt + n * 256 + chs * 8);
    }
  };

  auto readfrags = [&](int T, bf16x8* af, bf16x8* bfr) {
    const unsigned short* Ab = (const unsigned short*)(smem + (size_t)(T & 3) * 16384);
    const unsigned short* Bb = (const unsigned short*)(smem + 65536 + (size_t)(T & 3) * 16384);
    #pragma unroll
    for (int mi = 0; mi < 8; ++mi) af[mi] = *(const bf16x8*)(Ab + aoff[mi]);
    #pragma unroll
    for (int ni = 0; ni < 4; ++ni) bfr[ni] = *(const bf16x8*)(Bb + boff[ni]);
  };

  auto mfma32 = [&](bf16x8* af, bf16x8* bfr) {
    __builtin_amdgcn_s_setprio(1);
    #pragma unroll
    for (int mi = 0; mi < 8; ++mi)
      #pragma unroll
      for (int ni = 0; ni < 4; ++ni)
        acc[mi][ni] = __builtin_amdgcn_mfma_f32_16x16x32_bf16(
            af[mi], bfr[ni], acc[mi][ni], 0, 0, 0);
    __builtin_amdgcn_s_setprio(0);
  };

  // prologue: fill 3 ring slots; make stage(0) globally visible
  stage(0); stage(1); stage(2);
  asm volatile("s_waitcnt vmcnt(8)" ::: "memory");
  __builtin_amdgcn_s_barrier();
  asm volatile("" ::: "memory");
  __builtin_amdgcn_sched_barrier(0);

  for (int t = 0; t < 69; ++t) {
    bf16x8 af[8], bfr[4];
    readfrags(t, af, bfr);        // ds_read issue (latency hides under MFMAs)
    stage(t + 3);                 // global_load_lds issue
    __builtin_amdgcn_sched_barrier(0);
    mfma32(af, bfr);              // compiler lgkm-gates on frag arrival
    asm volatile("s_waitcnt vmcnt(8)" ::: "memory");  // stage(t+1) landed
    __builtin_amdgcn_s_barrier();
    asm volatile("" ::: "memory");
    __builtin_amdgcn_sched_barrier(0);
  }
  {  // t = 69: stage(72) doesn't exist; outstanding = {70,71}; guard 70
    bf16x8 af[8], bfr[4];
    readfrags(69, af, bfr);
    __builtin_amdgcn_sched_barrier(0);
    mfma32(af, bfr);
    asm volatile("s_waitcnt vmcnt(4)" ::: "memory");
    __builtin_amdgcn_s_barrier();
    asm volatile("" ::: "memory");
    __builtin_amdgcn_sched_barrier(0);
  }
  {  // t = 70: guard 71
    bf16x8 af[8], bfr[4];
    readfrags(70, af, bfr);
    __builtin_amdgcn_sched_barrier(0);
    mfma32(af, bfr);
    asm volatile("s_waitcnt vmcnt(0)" ::: "memory");
    __builtin_amdgcn_s_barrier();
    asm volatile("" ::: "memory");
    __builtin_amdgcn_sched_barrier(0);
  }
  {  // t = 71: final
    bf16x8 af[8], bfr[4];
    readfrags(71, af, bfr);
    __builtin_amdgcn_sched_barrier(0);
    mfma32(af, bfr);
  }

  // epilogue: +bias, fp32 store
  const int colg = wc * 64 + r15;
  float bias[4];
  #pragma unroll
  for (int ni = 0; ni < 4; ++ni) bias[ni] = b_def[colg + ni * 16];
  #pragma unroll
  for (int mi = 0; mi < 8; ++mi) {
    const int r0 = wr * 128 + mi * 16 + g4 * 4;
    #pragma unroll
    for (int j = 0; j < 4; ++j) {
      float* orow = out + ((size_t)mt * 256 + r0 + j) * 256 + colg;
      #pragma unroll
      for (int ni = 0; ni < 4; ++ni) orow[ni * 16] = acc[mi][ni][j] + bias[ni];
    }
  }
}

extern "C" void kernel_launch(void* const* d_in, const int* in_sizes, int n_in,
                              void* d_out, int out_size, void* d_ws, size_t ws_size,
                              hipStream_t stream) {
  const float* in = (const float*)d_in[0];     // (16,128,128,256)
  const float* w_off = (const float*)d_in[1];  // (3,3,256,2)
  const float* b_off = (const float*)d_in[2];  // (2,)
  const float* w_def = (const float*)d_in[3];  // (3,3,256,256)
  const float* b_def = (const float*)d_in[4];  // (256,)
  float* out = (float*)d_out;

  char* ws = (char*)d_ws;
  unsigned short* zerobuf = (unsigned short*)ws;                 // 4 KB zeros
  unsigned short* wT = (unsigned short*)(ws + 4096);             // 1,179,648 B
  unsigned short* samp = (unsigned short*)(ws + 4096 + 1179648); // 134,217,728 B

  hipMemsetAsync(ws, 0, 4096, stream);
  hipLaunchKernelGGL(k2_wT, dim3(2304), dim3(256), 0, stream, w_def, wT);
  hipLaunchKernelGGL(k1_offs_gather, dim3(2048), dim3(256), 0, stream,
                     in, w_off, b_off, samp);
  hipLaunchKernelGGL(k3_conv, dim3(1024), dim3(512), 0, stream,
                     samp, wT, b_def, out, zerobuf);
}

// Round 5
// 508.276 us; speedup vs baseline: 1.2973x; 1.0328x over previous
//
#include <hip/hip_runtime.h>
#include <hip/hip_bf16.h>

typedef __attribute__((ext_vector_type(8))) short bf16x8;
typedef __attribute__((ext_vector_type(4))) float f32x4;

__device__ __forceinline__ unsigned short f2bf(float f) {
  __hip_bfloat16 h = __float2bfloat16(f);
  return *reinterpret_cast<unsigned short*>(&h);
}

__device__ __forceinline__ void gld_lds16(void* lds, const void* g) {
  __builtin_amdgcn_global_load_lds(
      (const __attribute__((address_space(1))) unsigned int*)g,
      (__attribute__((address_space(3))) unsigned int*)lds, 16, 0, 0);
}

// ---------------------------------------------------------------------------
// Kernel 1: offset conv (fp64 accumulate) + gather + fp32->bf16 cast.
// (unchanged — at HBM floor: ~1.2 GB compulsory traffic ≈ 190 µs)
// ---------------------------------------------------------------------------
__global__ __launch_bounds__(256) void k1_offs_gather(
    const float* __restrict__ in, const float* __restrict__ w_off,
    const float* __restrict__ b_off, unsigned short* __restrict__ samp) {
  __shared__ float tile[3][128][34];
  __shared__ float wlf[9 * 64];
  __shared__ double dsum[2][128][2];
  __shared__ int lin_lds[128];

  const int bid = blockIdx.x;
  const int b = bid >> 7, h = bid & 127;
  const int t = threadIdx.x;
  const int w = t & 127, half = t >> 7, ch0 = half * 16;

  double a0 = 0.0, a1 = 0.0;

  for (int c0 = 0; c0 < 256; c0 += 32) {
    __syncthreads();
    for (int i = t; i < 576; i += 256) {
      int tap = i >> 6, r = i & 63;
      wlf[i] = w_off[tap * 512 + c0 * 2 + r];
    }
    for (int dr = 0; dr < 3; ++dr) {
      int hh = h + dr - 1;
      if ((unsigned)hh < 128u) {
        const float* rbase = in + ((size_t)(b * 128 + hh) * 128) * 256 + c0;
        #pragma unroll
        for (int it = 0; it < 4; ++it) {
          int idx = it * 256 + t;
          int ww = idx >> 3, cq = idx & 7;
          const float4 v = *(const float4*)(rbase + ww * 256 + cq * 4);
          float* dst = &tile[dr][ww][cq * 4];
          *(float2*)dst = make_float2(v.x, v.y);
          *(float2*)(dst + 2) = make_float2(v.z, v.w);
        }
      } else {
        #pragma unroll
        for (int it = 0; it < 4; ++it) {
          int idx = it * 256 + t;
          int ww = idx >> 3, cq = idx & 7;
          float* dst = &tile[dr][ww][cq * 4];
          *(float2*)dst = make_float2(0.f, 0.f);
          *(float2*)(dst + 2) = make_float2(0.f, 0.f);
        }
      }
    }
    __syncthreads();
    #pragma unroll
    for (int dr = 0; dr < 3; ++dr) {
      #pragma unroll
      for (int dc = 0; dc < 3; ++dc) {
        int wsrc = w + dc - 1;
        if ((unsigned)wsrc >= 128u) continue;
        const float2* tp2 = (const float2*)&tile[dr][wsrc][ch0];
        const float2* wp2 = (const float2*)&wlf[(dr * 3 + dc) * 64 + ch0 * 2];
        #pragma unroll
        for (int c2 = 0; c2 < 8; ++c2) {
          float2 v = tp2[c2];
          float2 wa = wp2[2 * c2];
          float2 wb = wp2[2 * c2 + 1];
          a0 += (double)v.x * (double)wa.x;
          a1 += (double)v.x * (double)wa.y;
          a0 += (double)v.y * (double)wb.x;
          a1 += (double)v.y * (double)wb.y;
        }
      }
    }
  }
  dsum[half][w][0] = a0;
  dsum[half][w][1] = a1;
  __syncthreads();
  if (t < 128) {
    double o0 = dsum[0][t][0] + dsum[1][t][0] + (double)b_off[0];
    double o1 = dsum[0][t][1] + dsum[1][t][1] + (double)b_off[1];
    double yd = (double)h + o0;
    double xd = (double)t + o1;
    yd = yd < 0.0 ? 0.0 : (yd > 127.0 ? 127.0 : yd);
    xd = xd < 0.0 ? 0.0 : (xd > 127.0 ? 127.0 : xd);
    int y = (int)yd, x = (int)xd;
    lin_lds[t] = y * 128 + x;
  }
  __syncthreads();
  const float* imgbase = in + (size_t)b * 16384 * 256;
  unsigned short* obase = samp + (size_t)bid * 128 * 256;
  for (int it = 0; it < 32; ++it) {
    int idx = it * 256 + t;
    int px = idx >> 6, cv = idx & 63;
    const float4 v = *(const float4*)(imgbase + (size_t)lin_lds[px] * 256 + cv * 4);
    ushort4 o;
    o.x = f2bf(v.x); o.y = f2bf(v.y); o.z = f2bf(v.z); o.w = f2bf(v.w);
    *(ushort4*)(obase + px * 256 + cv * 4) = o;
  }
}

// ---------------------------------------------------------------------------
// Kernel 2: w_def (3,3,256,256)[tap][k][n] fp32 -> wT[tap][n][k] bf16
// ---------------------------------------------------------------------------
__global__ __launch_bounds__(256) void k2_wT(const float* __restrict__ wdef,
                                             unsigned short* __restrict__ wT) {
  int g = blockIdx.x * 256 + threadIdx.x;
  int tap = g >> 16;
  int n = (g >> 8) & 255;
  int k = g & 255;
  wT[g] = f2bf(wdef[((size_t)tap * 256 + k) * 256 + n]);
}

// ---------------------------------------------------------------------------
// Kernel 3: implicit-GEMM 3x3 SAME conv, bf16 MFMA.
// BM=256, BN=256, BK=32, 72 K-steps. 8 waves (2M x 4N), per-wave 128x64.
// 4-deep LDS ring, single barrier/step:
//   reads(T) [B-first, A ascending] -> stage(T+3) -> 32 MFMA (lgkm-gated
//   incrementally) -> vmcnt(8) -> s_barrier.
// Round-5: staging address math hoisted (per-thread base ptrs + 9-bit tap
// validity mask; per-step only uniform delta adds), fragment reads ordered
// so MFMA(mi) gates on read 5+mi of 12 instead of read 9.
// Ledger (unchanged from round 4): vmcnt(8) leaves stages t+2,t+3 in
// flight, guarantees stage(t+1); slot WAR protected by trailing barrier.
// Tail: VM = 4 (T=69), 0 (T=70), none (T=71).
// ---------------------------------------------------------------------------
__global__ __launch_bounds__(512, 2) void k3_conv(
    const unsigned short* __restrict__ samp, const unsigned short* __restrict__ wT,
    const float* __restrict__ b_def, float* __restrict__ out,
    const unsigned short* __restrict__ zerobuf) {
  __shared__ __align__(16) unsigned char smem[131072];  // A ring 64KB | B ring 64KB

  // T1: bijective XCD swizzle (grid 1024 % 8 == 0)
  const int bid0 = blockIdx.x;
  const int mt = (bid0 & 7) * 128 + (bid0 >> 3);
  const int bimg = mt >> 6;
  const int h0 = (mt & 63) * 2;

  const int tid = threadIdx.x;
  const int lane = tid & 63, wave = tid >> 6;
  const int wr = wave >> 2, wc = wave & 3;
  const int r15 = lane & 15, g4 = lane >> 4;
  const int g4eff = g4 ^ ((r15 >> 1) & 3);   // read-side bank swizzle

  int aoff[8], boff[4];
  #pragma unroll
  for (int mi = 0; mi < 8; ++mi)
    aoff[mi] = (wr * 128 + mi * 16 + r15) * 32 + g4eff * 8;
  #pragma unroll
  for (int ni = 0; ni < 4; ++ni)
    boff[ni] = (wc * 64 + ni * 16 + r15) * 32 + g4eff * 8;

  // ---- staging precompute (hoisted out of the 72-step loop) ----
  const int chq = tid & 3;          // 16B chunk within 32-ch row
  const int pix = tid >> 2;         // 0..127: pixel (A) / out-channel row (B)
  const int chs = chq ^ ((pix >> 1) & 3);  // inverse swizzle on global source
  const unsigned short* pA[2];
  const unsigned short* pB[2];
  unsigned vmask[2];                // bit tap: A source in-bounds for this tap
  #pragma unroll
  for (int it = 0; it < 2; ++it) {
    const int hh = h0 + it;
    pA[it] = samp + ((size_t)(bimg * 128 + hh) * 128 + pix) * 256 + chs * 8;
    pB[it] = wT + (size_t)(it * 128 + pix) * 256 + chs * 8;
    unsigned m = 0;
    #pragma unroll
    for (int tap = 0; tap < 9; ++tap) {
      const int dr = tap / 3 - 1, dc = tap % 3 - 1;
      if ((unsigned)(hh + dr) < 128u && (unsigned)(pix + dc) < 128u)
        m |= 1u << tap;
    }
    vmask[it] = m;
  }
  const unsigned short* zb = zerobuf + chq * 8;

  f32x4 acc[8][4];
  #pragma unroll
  for (int i = 0; i < 8; ++i)
    #pragma unroll
    for (int j = 0; j < 4; ++j) acc[i][j] = (f32x4){0.f, 0.f, 0.f, 0.f};

  auto stage = [&](int ts) {
    const int tap = ts >> 3, kc = ts & 7;
    const int q = (tap * 11) >> 5;                 // tap/3 (uniform)
    const int tapdelta = ((q - 1) * 128 + (tap - q * 3 - 1)) * 256 + kc * 32;
    const int boffg = tap * 65536 + kc * 32;
    unsigned char* Ad = smem + (size_t)(ts & 3) * 16384;
    unsigned char* Bd = smem + 65536 + (size_t)(ts & 3) * 16384;
    #pragma unroll
    for (int it = 0; it < 2; ++it)
      gld_lds16(Bd + (it * 512 + tid) * 16, pB[it] + boffg);
    #pragma unroll
    for (int it = 0; it < 2; ++it) {
      const unsigned short* src =
          ((vmask[it] >> tap) & 1) ? (pA[it] + tapdelta) : zb;
      gld_lds16(Ad + (it * 512 + tid) * 16, src);
    }
  };

  auto readfrags = [&](int T, bf16x8* af, bf16x8* bfr) {
    const unsigned short* Ab = (const unsigned short*)(smem + (size_t)(T & 3) * 16384);
    const unsigned short* Bb = (const unsigned short*)(smem + 65536 + (size_t)(T & 3) * 16384);
    #pragma unroll
    for (int ni = 0; ni < 4; ++ni) bfr[ni] = *(const bf16x8*)(Bb + boff[ni]);
    #pragma unroll
    for (int mi = 0; mi < 8; ++mi) af[mi] = *(const bf16x8*)(Ab + aoff[mi]);
  };

  auto mfma32 = [&](bf16x8* af, bf16x8* bfr) {
    __builtin_amdgcn_s_setprio(1);
    #pragma unroll
    for (int mi = 0; mi < 8; ++mi)
      #pragma unroll
      for (int ni = 0; ni < 4; ++ni)
        acc[mi][ni] = __builtin_amdgcn_mfma_f32_16x16x32_bf16(
            af[mi], bfr[ni], acc[mi][ni], 0, 0, 0);
    __builtin_amdgcn_s_setprio(0);
  };

  // prologue: fill 3 ring slots; make stage(0) globally visible
  stage(0); stage(1); stage(2);
  asm volatile("s_waitcnt vmcnt(8)" ::: "memory");
  __builtin_amdgcn_s_barrier();
  asm volatile("" ::: "memory");
  __builtin_amdgcn_sched_barrier(0);

  for (int t = 0; t < 69; ++t) {
    bf16x8 af[8], bfr[4];
    readfrags(t, af, bfr);
    stage(t + 3);
    __builtin_amdgcn_sched_barrier(0);
    mfma32(af, bfr);
    asm volatile("s_waitcnt vmcnt(8)" ::: "memory");
    __builtin_amdgcn_s_barrier();
    asm volatile("" ::: "memory");
    __builtin_amdgcn_sched_barrier(0);
  }
  {  // t = 69
    bf16x8 af[8], bfr[4];
    readfrags(69, af, bfr);
    __builtin_amdgcn_sched_barrier(0);
    mfma32(af, bfr);
    asm volatile("s_waitcnt vmcnt(4)" ::: "memory");
    __builtin_amdgcn_s_barrier();
    asm volatile("" ::: "memory");
    __builtin_amdgcn_sched_barrier(0);
  }
  {  // t = 70
    bf16x8 af[8], bfr[4];
    readfrags(70, af, bfr);
    __builtin_amdgcn_sched_barrier(0);
    mfma32(af, bfr);
    asm volatile("s_waitcnt vmcnt(0)" ::: "memory");
    __builtin_amdgcn_s_barrier();
    asm volatile("" ::: "memory");
    __builtin_amdgcn_sched_barrier(0);
  }
  {  // t = 71
    bf16x8 af[8], bfr[4];
    readfrags(71, af, bfr);
    __builtin_amdgcn_sched_barrier(0);
    mfma32(af, bfr);
  }

  // epilogue: +bias, fp32 store
  const int colg = wc * 64 + r15;
  float bias[4];
  #pragma unroll
  for (int ni = 0; ni < 4; ++ni) bias[ni] = b_def[colg + ni * 16];
  #pragma unroll
  for (int mi = 0; mi < 8; ++mi) {
    const int r0 = wr * 128 + mi * 16 + g4 * 4;
    #pragma unroll
    for (int j = 0; j < 4; ++j) {
      float* orow = out + ((size_t)mt * 256 + r0 + j) * 256 + colg;
      #pragma unroll
      for (int ni = 0; ni < 4; ++ni) orow[ni * 16] = acc[mi][ni][j] + bias[ni];
    }
  }
}

extern "C" void kernel_launch(void* const* d_in, const int* in_sizes, int n_in,
                              void* d_out, int out_size, void* d_ws, size_t ws_size,
                              hipStream_t stream) {
  const float* in = (const float*)d_in[0];     // (16,128,128,256)
  const float* w_off = (const float*)d_in[1];  // (3,3,256,2)
  const float* b_off = (const float*)d_in[2];  // (2,)
  const float* w_def = (const float*)d_in[3];  // (3,3,256,256)
  const float* b_def = (const float*)d_in[4];  // (256,)
  float* out = (float*)d_out;

  char* ws = (char*)d_ws;
  unsigned short* zerobuf = (unsigned short*)ws;                 // 4 KB zeros
  unsigned short* wT = (unsigned short*)(ws + 4096);             // 1,179,648 B
  unsigned short* samp = (unsigned short*)(ws + 4096 + 1179648); // 134,217,728 B

  hipMemsetAsync(ws, 0, 4096, stream);
  hipLaunchKernelGGL(k2_wT, dim3(2304), dim3(256), 0, stream, w_def, wT);
  hipLaunchKernelGGL(k1_offs_gather, dim3(2048), dim3(256), 0, stream,
                     in, w_off, b_off, samp);
  hipLaunchKernelGGL(k3_conv, dim3(1024), dim3(512), 0, stream,
                     samp, wT, b_def, out, zerobuf);
}